// Round 4
// baseline (4292.422 us; speedup 1.0000x reference)
//
#include <hip/hip_runtime.h>
#include <hip/hip_bf16.h>
#include <math.h>

// Problem constants (fixed by reference)
#define N_   65536
#define F_   64
#define H_   128
#define E_   30000
#define NT_  5
#define ET_  10
#define NG_  50
#define L_   3
#define TL_  2
#define NH_  4
#define DH_  32
#define NB_  1024
#define TT_  64
#define FF_  512
#define CH_  512    // temporal node chunk

#define SCALE_ 0.17677669529663687f   // 1/sqrt(32)

__device__ __forceinline__ float gelu_exact(float x) {
    return 0.5f * x * (1.0f + erff(x * 0.70710678118654752f));
}
__device__ __forceinline__ void f4fma(float4& a, float s, const float4& b) {
    a.x += s * b.x; a.y += s * b.y; a.z += s * b.z; a.w += s * b.w;
}
__device__ __forceinline__ void f4scale(float4& a, float s) {
    a.x *= s; a.y *= s; a.z *= s; a.w *= s;
}
__device__ __forceinline__ float4 f4zero() { return make_float4(0.f, 0.f, 0.f, 0.f); }

// ---------------- grouping ----------------

__global__ void k_zero_cnt(int* cnt) {
    if (threadIdx.x < NG_) cnt[threadIdx.x] = 0;
}

__global__ void k_hist(const int* __restrict__ edge_index, const int* __restrict__ edge_type,
                       const int* __restrict__ node_type, int* __restrict__ gedge, int* __restrict__ cnt) {
    int e = blockIdx.x * blockDim.x + threadIdx.x;
    if (e >= E_) return;
    int dn = edge_index[E_ + e];
    int g = edge_type[e] * NT_ + node_type[dn];
    gedge[e] = g;
    atomicAdd(&cnt[g], 1);
}

__global__ void k_scan(const int* __restrict__ cnt, int* __restrict__ offs, int* __restrict__ curs) {
    if (threadIdx.x == 0 && blockIdx.x == 0) {
        int acc = 0;
        for (int g = 0; g < NG_; ++g) { offs[g] = acc; curs[g] = acc; acc += cnt[g]; }
        offs[NG_] = acc;
    }
}

__global__ void k_scatter(const int* __restrict__ gedge, int* __restrict__ curs,
                          int* __restrict__ sorted, int* __restrict__ gpos) {
    int e = blockIdx.x * blockDim.x + threadIdx.x;
    if (e >= E_) return;
    int g = gedge[e];
    int pos = atomicAdd(&curs[g], 1);
    sorted[pos] = e;
    gpos[pos] = g;
}

// descriptor lists: 64-edge tiles (qkv gemm + attention)
__global__ void k_desc(const int* __restrict__ offs, int2* __restrict__ desc64, int* __restrict__ nd64) {
    if (threadIdx.x || blockIdx.x) return;
    int n64 = 0;
    for (int g = 0; g < NG_; ++g) {
        int sz = offs[g + 1] - offs[g];
        for (int qs = 0; qs < sz; qs += 64) desc64[n64++] = make_int2(g, qs);
    }
    nd64[0] = n64;
}

// ---------------- input projection ----------------

__global__ void k_inproj(const float* __restrict__ x, const int* __restrict__ node_type,
                         const float* __restrict__ W_in, const float* __restrict__ b_in,
                         float* __restrict__ h) {
    int n = blockIdx.x;
    int j = threadIdx.x;  // 0..127
    __shared__ float sx[F_];
    if (j < F_) sx[j] = x[(size_t)n * F_ + j];
    __syncthreads();
    int nt = node_type[n];
    const float* W = W_in + (size_t)nt * F_ * H_;
    float acc = b_in[(size_t)nt * H_ + j];
    #pragma unroll 8
    for (int f = 0; f < F_; ++f) acc += sx[f] * W[(size_t)f * H_ + j];
    h[(size_t)n * H_ + j] = acc;
}

__global__ void k_zero(float* __restrict__ p, int n) {
    int i = blockIdx.x * blockDim.x + threadIdx.x;
    int stride = gridDim.x * blockDim.x;
    for (; i < n; i += stride) p[i] = 0.0f;
}

// ---------------- spatial qkv projection: tiled GEMM over 64-edge tiles ----------------
// grid = (tiles, 3); y: 0=q (dst rows), 1=k, 2=v (src rows)

__global__ __launch_bounds__(256) void k_sqkv_gemm(
    const float* __restrict__ h, const float* __restrict__ s_in_w, const float* __restrict__ s_in_b,
    const int* __restrict__ sorted, const int* __restrict__ offs, const int* __restrict__ edge_index,
    const int2* __restrict__ desc64, const int* __restrict__ nd64,
    float* __restrict__ qkv, int li) {
    int bx = blockIdx.x;
    if (bx >= nd64[0]) return;
    int2 dd = desc64[bx];
    int g = dd.x, qs = dd.y;
    int qbase = offs[g] + qs;
    int qcnt = min(64, offs[g + 1] - qbase);
    int et = g / NT_;
    int nt = blockIdx.y;
    __shared__ float s_a[64 * 132];
    __shared__ float s_b[32 * 132];
    int tid = threadIdx.x;
    // gather 64 input rows (dst for q, src for k/v)
    #pragma unroll
    for (int i = 0; i < 8; ++i) {
        int idx = i * 256 + tid;
        int r = idx >> 5, c4 = (idx & 31) * 4;
        int p = qbase + min(r, qcnt - 1);
        int e = sorted[p];
        int node = (nt == 0) ? edge_index[E_ + e] : edge_index[e];
        *reinterpret_cast<float4*>(&s_a[r * 132 + c4]) =
            *reinterpret_cast<const float4*>(&h[(size_t)node * H_ + c4]);
    }
    const float* B = s_in_w + ((size_t)(li * ET_ + et) * 3 * H_ + nt * H_) * H_;
    const float* bi = s_in_b + (size_t)(li * ET_ + et) * 3 * H_ + nt * H_;
    int rg = tid >> 4, cg = tid & 15;
    int r0 = rg * 4;
    float4 alo[4], ahi[4];
    #pragma unroll
    for (int rr = 0; rr < 4; ++rr) { alo[rr] = f4zero(); ahi[rr] = f4zero(); }
    for (int kci = 0; kci < 4; ++kci) {
        __syncthreads();
        #pragma unroll
        for (int i = 0; i < 4; ++i) {
            int idx = i * 256 + tid;
            int jj = idx >> 3, k4 = (idx & 7) * 4;
            float4 w = *reinterpret_cast<const float4*>(&B[(size_t)jj * H_ + kci * 32 + k4]);
            s_b[(k4 + 0) * 132 + jj] = w.x; s_b[(k4 + 1) * 132 + jj] = w.y;
            s_b[(k4 + 2) * 132 + jj] = w.z; s_b[(k4 + 3) * 132 + jj] = w.w;
        }
        __syncthreads();
        #pragma unroll
        for (int k4 = 0; k4 < 8; ++k4) {
            float4 a4[4];
            #pragma unroll
            for (int rr = 0; rr < 4; ++rr)
                a4[rr] = *reinterpret_cast<const float4*>(&s_a[(r0 + rr) * 132 + kci * 32 + k4 * 4]);
            #pragma unroll
            for (int jj = 0; jj < 4; ++jj) {
                float4 blo = *reinterpret_cast<const float4*>(&s_b[(k4 * 4 + jj) * 132 + cg * 4]);
                float4 bhi = *reinterpret_cast<const float4*>(&s_b[(k4 * 4 + jj) * 132 + 64 + cg * 4]);
                #pragma unroll
                for (int rr = 0; rr < 4; ++rr) {
                    float av = (jj == 0) ? a4[rr].x : (jj == 1) ? a4[rr].y : (jj == 2) ? a4[rr].z : a4[rr].w;
                    f4fma(alo[rr], av, blo);
                    f4fma(ahi[rr], av, bhi);
                }
            }
        }
    }
    float4 blo = *reinterpret_cast<const float4*>(&bi[cg * 4]);
    float4 bhi = *reinterpret_cast<const float4*>(&bi[64 + cg * 4]);
    #pragma unroll
    for (int rr = 0; rr < 4; ++rr) {
        int row = r0 + rr;
        if (row < qcnt) {
            float* op = qkv + (size_t)(qbase + row) * 384 + nt * H_;
            float4 lo = alo[rr], hi = ahi[rr];
            lo.x += blo.x; lo.y += blo.y; lo.z += blo.z; lo.w += blo.w;
            hi.x += bhi.x; hi.y += bhi.y; hi.z += bhi.z; hi.w += bhi.w;
            *reinterpret_cast<float4*>(op + cg * 4) = lo;
            *reinterpret_cast<float4*>(op + 64 + cg * 4) = hi;
        }
    }
}

// ---------------- grouped spatial attention + out-proj + scatter ----------------
// block = one (group, 64-query tile); 128 threads = 4 heads x 32 lanes, 2 queries/thread

__global__ __launch_bounds__(128, 2) void k_gattn(
    const float* __restrict__ qkv, const int* __restrict__ sorted,
    const int* __restrict__ offs, const int* __restrict__ edge_index,
    const int2* __restrict__ desc, const int* __restrict__ ndesc,
    const float* __restrict__ s_out_w, const float* __restrict__ s_out_b,
    float* __restrict__ h_new, int li) {
    int bx = blockIdx.x;
    if (bx >= ndesc[0]) return;
    int2 dd = desc[bx];
    int g = dd.x, qs = dd.y;
    int start = offs[g], end = offs[g + 1];
    int qbase = start + qs;
    int qcnt = min(64, end - qbase);
    int et = g / NT_;
    // union buffer: during attention = s_k[32*132] ++ s_v[32*132]; after = s_o[64*132]
    __shared__ float s_buf[64 * 132];
    __shared__ int s_dn[64];
    float* s_k = s_buf;
    float* s_v = s_buf + 32 * 132;
    float* s_o = s_buf;
    int tid = threadIdx.x;
    int head = tid >> 5, qi = tid & 31;

    if (tid < 64) {
        int p = qbase + min(tid, qcnt - 1);
        int e = sorted[p];
        s_dn[tid] = edge_index[E_ + e];
    }

    int p0 = qbase + min(qi, qcnt - 1);
    int p1 = qbase + min(qi + 32, qcnt - 1);
    float4 q0[8], q1[8];
    {
        const float4* qr0 = reinterpret_cast<const float4*>(&qkv[(size_t)p0 * 384 + head * DH_]);
        const float4* qr1 = reinterpret_cast<const float4*>(&qkv[(size_t)p1 * 384 + head * DH_]);
        #pragma unroll
        for (int i = 0; i < 8; ++i) { q0[i] = qr0[i]; q1[i] = qr1[i]; }
    }
    float m0 = -1e30f, m1 = -1e30f, ssum0 = 0.0f, ssum1 = 0.0f;
    float4 o0[8], o1[8];
    #pragma unroll
    for (int i = 0; i < 8; ++i) { o0[i] = f4zero(); o1[i] = f4zero(); }

    int nkt = (end - start + 31) >> 5;
    for (int kt = 0; kt < nkt; ++kt) {
        int kb = start + kt * 32;
        int kcnt = min(32, end - kb);
        __syncthreads();
        // stage k,v (32 rows x 256 floats)
        for (int i = 0; i < 16; ++i) {
            int idx = i * 128 + tid;
            int row = idx >> 6, c4 = idx & 63;
            if (row < kcnt) {
                float4 w = *reinterpret_cast<const float4*>(&qkv[(size_t)(kb + row) * 384 + 128 + c4 * 4]);
                int c = c4 * 4;
                float* dp = (c < 128) ? &s_k[row * 132 + c] : &s_v[row * 132 + (c - 128)];
                dp[0] = w.x; dp[1] = w.y; dp[2] = w.z; dp[3] = w.w;
            }
        }
        __syncthreads();
        if (kcnt == 32) {
            // single pass: scores in statically-indexed registers (2 queries)
            float sc0[32], sc1[32];
            float tmax0 = -1e30f, tmax1 = -1e30f;
            #pragma unroll
            for (int t2 = 0; t2 < 32; ++t2) {
                const float4* kr = reinterpret_cast<const float4*>(&s_k[t2 * 132 + head * DH_]);
                float a0 = 0, a1 = 0, b0 = 0, b1 = 0;
                #pragma unroll
                for (int i = 0; i < 8; ++i) {
                    float4 kk = kr[i];
                    a0 += q0[i].x * kk.x + q0[i].y * kk.y;
                    b0 += q0[i].z * kk.z + q0[i].w * kk.w;
                    a1 += q1[i].x * kk.x + q1[i].y * kk.y;
                    b1 += q1[i].z * kk.z + q1[i].w * kk.w;
                }
                float d0 = (a0 + b0) * SCALE_;
                float d1 = (a1 + b1) * SCALE_;
                sc0[t2] = d0; sc1[t2] = d1;
                tmax0 = fmaxf(tmax0, d0);
                tmax1 = fmaxf(tmax1, d1);
            }
            float mn0 = fmaxf(m0, tmax0), mn1 = fmaxf(m1, tmax1);
            float f0 = __expf(m0 - mn0), f1 = __expf(m1 - mn1);
            ssum0 *= f0; ssum1 *= f1;
            #pragma unroll
            for (int i = 0; i < 8; ++i) { f4scale(o0[i], f0); f4scale(o1[i], f1); }
            #pragma unroll
            for (int t2 = 0; t2 < 32; ++t2) {
                float e0 = __expf(sc0[t2] - mn0);
                float e1 = __expf(sc1[t2] - mn1);
                ssum0 += e0; ssum1 += e1;
                const float4* vr = reinterpret_cast<const float4*>(&s_v[t2 * 132 + head * DH_]);
                #pragma unroll
                for (int i = 0; i < 8; ++i) {
                    float4 vv = vr[i];
                    f4fma(o0[i], e0, vv);
                    f4fma(o1[i], e1, vv);
                }
            }
            m0 = mn0; m1 = mn1;
        } else {
            // tail: two-pass recompute
            float tmax0 = -1e30f, tmax1 = -1e30f;
            for (int t2 = 0; t2 < kcnt; ++t2) {
                const float4* kr = reinterpret_cast<const float4*>(&s_k[t2 * 132 + head * DH_]);
                float a0 = 0, a1 = 0, b0 = 0, b1 = 0;
                #pragma unroll
                for (int i = 0; i < 8; ++i) {
                    float4 kk = kr[i];
                    a0 += q0[i].x * kk.x + q0[i].y * kk.y;
                    b0 += q0[i].z * kk.z + q0[i].w * kk.w;
                    a1 += q1[i].x * kk.x + q1[i].y * kk.y;
                    b1 += q1[i].z * kk.z + q1[i].w * kk.w;
                }
                tmax0 = fmaxf(tmax0, (a0 + b0) * SCALE_);
                tmax1 = fmaxf(tmax1, (a1 + b1) * SCALE_);
            }
            float mn0 = fmaxf(m0, tmax0), mn1 = fmaxf(m1, tmax1);
            float f0 = __expf(m0 - mn0), f1 = __expf(m1 - mn1);
            ssum0 *= f0; ssum1 *= f1;
            #pragma unroll
            for (int i = 0; i < 8; ++i) { f4scale(o0[i], f0); f4scale(o1[i], f1); }
            for (int t2 = 0; t2 < kcnt; ++t2) {
                const float4* kr = reinterpret_cast<const float4*>(&s_k[t2 * 132 + head * DH_]);
                float a0 = 0, a1 = 0, b0 = 0, b1 = 0;
                #pragma unroll
                for (int i = 0; i < 8; ++i) {
                    float4 kk = kr[i];
                    a0 += q0[i].x * kk.x + q0[i].y * kk.y;
                    b0 += q0[i].z * kk.z + q0[i].w * kk.w;
                    a1 += q1[i].x * kk.x + q1[i].y * kk.y;
                    b1 += q1[i].z * kk.z + q1[i].w * kk.w;
                }
                float e0 = __expf((a0 + b0) * SCALE_ - mn0);
                float e1 = __expf((a1 + b1) * SCALE_ - mn1);
                ssum0 += e0; ssum1 += e1;
                const float4* vr = reinterpret_cast<const float4*>(&s_v[t2 * 132 + head * DH_]);
                #pragma unroll
                for (int i = 0; i < 8; ++i) {
                    float4 vv = vr[i];
                    f4fma(o0[i], e0, vv);
                    f4fma(o1[i], e1, vv);
                }
            }
            m0 = mn0; m1 = mn1;
        }
    }
    __syncthreads();   // all reads of s_k/s_v done before s_o overwrites the buffer
    float inv0 = 1.0f / ssum0;
    float inv1 = 1.0f / ssum1;
    #pragma unroll
    for (int i = 0; i < 8; ++i) {
        if (qi < qcnt) {
            float4 t = o0[i]; f4scale(t, inv0);
            *reinterpret_cast<float4*>(&s_o[qi * 132 + head * DH_ + i * 4]) = t;
        }
        if (qi + 32 < qcnt) {
            float4 t = o1[i]; f4scale(t, inv1);
            *reinterpret_cast<float4*>(&s_o[(qi + 32) * 132 + head * DH_ + i * 4]) = t;
        }
    }
    __syncthreads();
    // out-projection: thread = col tid; two chunks of 32 queries
    {
        const float* Wo = s_out_w + ((size_t)(li * ET_ + et) * H_ + tid) * H_;
        float bo = s_out_b[(size_t)(li * ET_ + et) * H_ + tid];
        for (int ch = 0; ch < 2; ++ch) {
            float acc[32];
            #pragma unroll
            for (int qq = 0; qq < 32; ++qq) acc[qq] = bo;
            #pragma unroll 8
            for (int k4 = 0; k4 < 32; ++k4) {
                float4 w = *reinterpret_cast<const float4*>(&Wo[k4 * 4]);
                #pragma unroll
                for (int qq = 0; qq < 32; ++qq) {
                    float4 ov = *reinterpret_cast<const float4*>(&s_o[(ch * 32 + qq) * 132 + k4 * 4]);
                    acc[qq] += w.x * ov.x + w.y * ov.y + w.z * ov.z + w.w * ov.w;
                }
            }
            #pragma unroll
            for (int qq = 0; qq < 32; ++qq) {
                int qrow = ch * 32 + qq;
                if (qrow < qcnt) {
                    atomicAdd(&h_new[(size_t)s_dn[qrow] * H_ + tid], acc[qq]);
                }
            }
        }
    }
}

// ---------------- LN + exact GELU + residual (spatial) ----------------

__global__ void k_lngelu(const float* __restrict__ h_new, float* __restrict__ h,
                         const float* __restrict__ ln_g, const float* __restrict__ ln_b, int li) {
    int n = blockIdx.x;
    int l = threadIdx.x;  // 0..63
    float v0 = h_new[(size_t)n * H_ + l];
    float v1 = h_new[(size_t)n * H_ + 64 + l];
    float s = v0 + v1;
    #pragma unroll
    for (int off = 32; off; off >>= 1) s += __shfl_xor(s, off);
    float mean = s * (1.0f / H_);
    float d0 = v0 - mean, d1 = v1 - mean;
    float vs = d0 * d0 + d1 * d1;
    #pragma unroll
    for (int off = 32; off; off >>= 1) vs += __shfl_xor(vs, off);
    float rstd = rsqrtf(vs * (1.0f / H_) + 1e-5f);
    const float* gg = ln_g + (size_t)li * H_;
    const float* bb = ln_b + (size_t)li * H_;
    float t0 = gelu_exact(d0 * rstd * gg[l] + bb[l]);
    float t1 = gelu_exact(d1 * rstd * gg[64 + l] + bb[64 + l]);
    size_t o = (size_t)n * H_;
    if (li == 0) { h[o + l] = t0; h[o + 64 + l] = t1; }
    else         { h[o + l] += t0; h[o + 64 + l] += t1; }
}

// ---------------- temporal: positional encoding add (in place on h) ----------------

__global__ void k_peadd(float* __restrict__ h) {
    int i = blockIdx.x * blockDim.x + threadIdx.x;
    int stride = gridDim.x * blockDim.x;
    for (; i < N_ * H_; i += stride) {
        int j = i & 127;
        int t = (i >> 7) & 63;
        float dv = __expf((float)(j & ~1) * (-0.0719557841560639f));
        float ang = (float)t * dv;
        float pe = (j & 1) ? cosf(ang) : sinf(ang);
        h[i] += pe;
    }
}

// ---------------- temporal qkv GEMM: block = (node-in-chunk, {q,k,v}) ----------------

__global__ __launch_bounds__(256) void k_tqkv(const float* __restrict__ hs,
                                              const float* __restrict__ t_in_w, const float* __restrict__ t_in_b,
                                              float* __restrict__ qc, float* __restrict__ kc, float* __restrict__ vc,
                                              int li, int c0) {
    int nb = blockIdx.x;        // node in chunk
    int nt = blockIdx.y;        // 0=q 1=k 2=v
    int node = c0 + nb;
    __shared__ float s_a[64 * 132];
    __shared__ float s_b[32 * 132];
    int tid = threadIdx.x;
    // stage A: node's 64x128 hs tile
    #pragma unroll
    for (int i = 0; i < 8; ++i) {
        int idx = i * 256 + tid;
        int r = idx >> 5, c4 = (idx & 31) * 4;
        *reinterpret_cast<float4*>(&s_a[r * 132 + c4]) =
            *reinterpret_cast<const float4*>(&hs[((size_t)node * 64 + r) * 128 + c4]);
    }
    const float* B = t_in_w + ((size_t)li * 384 + nt * 128) * 128;
    const float* bi = t_in_b + (size_t)li * 384 + nt * 128;
    int rg = tid >> 4, cg = tid & 15;
    int r0 = rg * 4;
    float4 alo[4], ahi[4];
    #pragma unroll
    for (int rr = 0; rr < 4; ++rr) { alo[rr] = f4zero(); ahi[rr] = f4zero(); }
    for (int kci = 0; kci < 4; ++kci) {
        __syncthreads();
        #pragma unroll
        for (int i = 0; i < 4; ++i) {
            int idx = i * 256 + tid;
            int jj = idx >> 3, k4 = (idx & 7) * 4;
            float4 w = *reinterpret_cast<const float4*>(&B[(size_t)jj * 128 + kci * 32 + k4]);
            s_b[(k4 + 0) * 132 + jj] = w.x; s_b[(k4 + 1) * 132 + jj] = w.y;
            s_b[(k4 + 2) * 132 + jj] = w.z; s_b[(k4 + 3) * 132 + jj] = w.w;
        }
        __syncthreads();
        #pragma unroll
        for (int k4 = 0; k4 < 8; ++k4) {
            float4 a4[4];
            #pragma unroll
            for (int rr = 0; rr < 4; ++rr)
                a4[rr] = *reinterpret_cast<const float4*>(&s_a[(r0 + rr) * 132 + kci * 32 + k4 * 4]);
            #pragma unroll
            for (int jj = 0; jj < 4; ++jj) {
                float4 blo = *reinterpret_cast<const float4*>(&s_b[(k4 * 4 + jj) * 132 + cg * 4]);
                float4 bhi = *reinterpret_cast<const float4*>(&s_b[(k4 * 4 + jj) * 132 + 64 + cg * 4]);
                #pragma unroll
                for (int rr = 0; rr < 4; ++rr) {
                    float av = (jj == 0) ? a4[rr].x : (jj == 1) ? a4[rr].y : (jj == 2) ? a4[rr].z : a4[rr].w;
                    f4fma(alo[rr], av, blo);
                    f4fma(ahi[rr], av, bhi);
                }
            }
        }
    }
    float* dst = (nt == 0) ? qc : (nt == 1) ? kc : vc;
    float sc = (nt == 0) ? SCALE_ : 1.0f;
    float4 blo = *reinterpret_cast<const float4*>(&bi[cg * 4]);
    float4 bhi = *reinterpret_cast<const float4*>(&bi[64 + cg * 4]);
    #pragma unroll
    for (int rr = 0; rr < 4; ++rr) {
        float4 lo = alo[rr], hi = ahi[rr];
        lo.x = (lo.x + blo.x) * sc; lo.y = (lo.y + blo.y) * sc; lo.z = (lo.z + blo.z) * sc; lo.w = (lo.w + blo.w) * sc;
        hi.x = (hi.x + bhi.x) * sc; hi.y = (hi.y + bhi.y) * sc; hi.z = (hi.z + bhi.z) * sc; hi.w = (hi.w + bhi.w) * sc;
        size_t row = (size_t)nb * 64 + r0 + rr;
        *reinterpret_cast<float4*>(&dst[row * 128 + cg * 4]) = lo;
        *reinterpret_cast<float4*>(&dst[row * 128 + 64 + cg * 4]) = hi;
    }
}

// ---------------- temporal attention: block = (node-in-chunk, head), 64 threads ----------------

__global__ __launch_bounds__(64) void k_tattn(float* __restrict__ qc, const float* __restrict__ kc,
                                              const float* __restrict__ vc) {
    int nb = blockIdx.x, head = blockIdx.y;
    __shared__ float s_k[64 * 36];
    __shared__ float s_v[64 * 36];
    int t = threadIdx.x;
    #pragma unroll
    for (int i = 0; i < 8; ++i) {
        int idx = i * 64 + t;
        int row = idx >> 3, d4 = (idx & 7) * 4;
        *reinterpret_cast<float4*>(&s_k[row * 36 + d4]) =
            *reinterpret_cast<const float4*>(&kc[((size_t)nb * 64 + row) * 128 + head * DH_ + d4]);
        *reinterpret_cast<float4*>(&s_v[row * 36 + d4]) =
            *reinterpret_cast<const float4*>(&vc[((size_t)nb * 64 + row) * 128 + head * DH_ + d4]);
    }
    float4 q[8];
    {
        const float4* qr = reinterpret_cast<const float4*>(&qc[((size_t)nb * 64 + t) * 128 + head * DH_]);
        #pragma unroll
        for (int i = 0; i < 8; ++i) q[i] = qr[i];
    }
    __syncthreads();
    // pass 1: max
    float m = -1e30f;
    for (int t2 = 0; t2 < 64; ++t2) {
        const float4* kr = reinterpret_cast<const float4*>(&s_k[t2 * 36]);
        float s0 = 0, s1 = 0, s2 = 0, s3 = 0;
        #pragma unroll
        for (int i = 0; i < 8; ++i) {
            float4 kk = kr[i];
            s0 += q[i].x * kk.x; s1 += q[i].y * kk.y; s2 += q[i].z * kk.z; s3 += q[i].w * kk.w;
        }
        m = fmaxf(m, (s0 + s1) + (s2 + s3));
    }
    // pass 2: exp + PV
    float ssum = 0.0f;
    float4 o[8];
    #pragma unroll
    for (int i = 0; i < 8; ++i) o[i] = f4zero();
    for (int t2 = 0; t2 < 64; ++t2) {
        const float4* kr = reinterpret_cast<const float4*>(&s_k[t2 * 36]);
        float s0 = 0, s1 = 0, s2 = 0, s3 = 0;
        #pragma unroll
        for (int i = 0; i < 8; ++i) {
            float4 kk = kr[i];
            s0 += q[i].x * kk.x; s1 += q[i].y * kk.y; s2 += q[i].z * kk.z; s3 += q[i].w * kk.w;
        }
        float p = __expf((s0 + s1) + (s2 + s3) - m);
        ssum += p;
        const float4* vr = reinterpret_cast<const float4*>(&s_v[t2 * 36]);
        #pragma unroll
        for (int i = 0; i < 8; ++i) f4fma(o[i], p, vr[i]);
    }
    float inv = 1.0f / ssum;
    float4* orow = reinterpret_cast<float4*>(&qc[((size_t)nb * 64 + t) * 128 + head * DH_]);
    #pragma unroll
    for (int i = 0; i < 8; ++i) { float4 v = o[i]; f4scale(v, inv); orow[i] = v; }
}

// ---------------- temporal out-proj + residual + LN1 ----------------

__global__ __launch_bounds__(256) void k_toutln(const float* __restrict__ oc, float* __restrict__ hs,
                                                const float* __restrict__ t_out_w, const float* __restrict__ t_out_b,
                                                const float* __restrict__ ln_g, const float* __restrict__ ln_b,
                                                int li, int c0) {
    int nb = blockIdx.x;
    int node = c0 + nb;
    __shared__ float s_a[64 * 132];
    __shared__ float s_b[32 * 132];
    int tid = threadIdx.x;
    #pragma unroll
    for (int i = 0; i < 8; ++i) {
        int idx = i * 256 + tid;
        int r = idx >> 5, c4 = (idx & 31) * 4;
        *reinterpret_cast<float4*>(&s_a[r * 132 + c4]) =
            *reinterpret_cast<const float4*>(&oc[((size_t)nb * 64 + r) * 128 + c4]);
    }
    const float* B = t_out_w + (size_t)li * 128 * 128;
    const float* bo = t_out_b + (size_t)li * 128;
    int rg = tid >> 4, cg = tid & 15;
    int r0 = rg * 4;
    float4 alo[4], ahi[4];
    #pragma unroll
    for (int rr = 0; rr < 4; ++rr) { alo[rr] = f4zero(); ahi[rr] = f4zero(); }
    for (int kci = 0; kci < 4; ++kci) {
        __syncthreads();
        #pragma unroll
        for (int i = 0; i < 4; ++i) {
            int idx = i * 256 + tid;
            int jj = idx >> 3, k4 = (idx & 7) * 4;
            float4 w = *reinterpret_cast<const float4*>(&B[(size_t)jj * 128 + kci * 32 + k4]);
            s_b[(k4 + 0) * 132 + jj] = w.x; s_b[(k4 + 1) * 132 + jj] = w.y;
            s_b[(k4 + 2) * 132 + jj] = w.z; s_b[(k4 + 3) * 132 + jj] = w.w;
        }
        __syncthreads();
        #pragma unroll
        for (int k4 = 0; k4 < 8; ++k4) {
            float4 a4[4];
            #pragma unroll
            for (int rr = 0; rr < 4; ++rr)
                a4[rr] = *reinterpret_cast<const float4*>(&s_a[(r0 + rr) * 132 + kci * 32 + k4 * 4]);
            #pragma unroll
            for (int jj = 0; jj < 4; ++jj) {
                float4 blo = *reinterpret_cast<const float4*>(&s_b[(k4 * 4 + jj) * 132 + cg * 4]);
                float4 bhi = *reinterpret_cast<const float4*>(&s_b[(k4 * 4 + jj) * 132 + 64 + cg * 4]);
                #pragma unroll
                for (int rr = 0; rr < 4; ++rr) {
                    float av = (jj == 0) ? a4[rr].x : (jj == 1) ? a4[rr].y : (jj == 2) ? a4[rr].z : a4[rr].w;
                    f4fma(alo[rr], av, blo);
                    f4fma(ahi[rr], av, bhi);
                }
            }
        }
    }
    float4 bblo = *reinterpret_cast<const float4*>(&bo[cg * 4]);
    float4 bbhi = *reinterpret_cast<const float4*>(&bo[64 + cg * 4]);
    float4 glo = *reinterpret_cast<const float4*>(&ln_g[(size_t)li * 128 + cg * 4]);
    float4 ghi = *reinterpret_cast<const float4*>(&ln_g[(size_t)li * 128 + 64 + cg * 4]);
    float4 lblo = *reinterpret_cast<const float4*>(&ln_b[(size_t)li * 128 + cg * 4]);
    float4 lbhi = *reinterpret_cast<const float4*>(&ln_b[(size_t)li * 128 + 64 + cg * 4]);
    #pragma unroll
    for (int rr = 0; rr < 4; ++rr) {
        size_t row = (size_t)node * 64 + r0 + rr;
        float4 rlo = *reinterpret_cast<const float4*>(&hs[row * 128 + cg * 4]);
        float4 rhi = *reinterpret_cast<const float4*>(&hs[row * 128 + 64 + cg * 4]);
        float4 lo = alo[rr], hi = ahi[rr];
        lo.x += bblo.x + rlo.x; lo.y += bblo.y + rlo.y; lo.z += bblo.z + rlo.z; lo.w += bblo.w + rlo.w;
        hi.x += bbhi.x + rhi.x; hi.y += bbhi.y + rhi.y; hi.z += bbhi.z + rhi.z; hi.w += bbhi.w + rhi.w;
        float s = lo.x + lo.y + lo.z + lo.w + hi.x + hi.y + hi.z + hi.w;
        s += __shfl_xor(s, 1); s += __shfl_xor(s, 2); s += __shfl_xor(s, 4); s += __shfl_xor(s, 8);
        float mean = s * (1.0f / 128.0f);
        float4 dlo = make_float4(lo.x - mean, lo.y - mean, lo.z - mean, lo.w - mean);
        float4 dhi = make_float4(hi.x - mean, hi.y - mean, hi.z - mean, hi.w - mean);
        float vx = dlo.x * dlo.x + dlo.y * dlo.y + dlo.z * dlo.z + dlo.w * dlo.w +
                   dhi.x * dhi.x + dhi.y * dhi.y + dhi.z * dhi.z + dhi.w * dhi.w;
        vx += __shfl_xor(vx, 1); vx += __shfl_xor(vx, 2); vx += __shfl_xor(vx, 4); vx += __shfl_xor(vx, 8);
        float rstd = rsqrtf(vx * (1.0f / 128.0f) + 1e-5f);
        float4 olo = make_float4(dlo.x * rstd * glo.x + lblo.x, dlo.y * rstd * glo.y + lblo.y,
                                 dlo.z * rstd * glo.z + lblo.z, dlo.w * rstd * glo.w + lblo.w);
        float4 ohi = make_float4(dhi.x * rstd * ghi.x + lbhi.x, dhi.y * rstd * ghi.y + lbhi.y,
                                 dhi.z * rstd * ghi.z + lbhi.z, dhi.w * rstd * ghi.w + lbhi.w);
        *reinterpret_cast<float4*>(&hs[row * 128 + cg * 4]) = olo;
        *reinterpret_cast<float4*>(&hs[row * 128 + 64 + cg * 4]) = ohi;
    }
}

// ---------------- temporal fused FF (FF1+gelu+FF2) + residual + LN2 ----------------

__global__ __launch_bounds__(256) void k_tff(float* __restrict__ hs,
                                             const float* __restrict__ t_w1, const float* __restrict__ t_b1,
                                             const float* __restrict__ t_w2, const float* __restrict__ t_b2,
                                             const float* __restrict__ ln_g, const float* __restrict__ ln_b,
                                             int li) {
    int node = blockIdx.x;
    __shared__ float s_h[64 * 132];
    __shared__ float s_f[64 * 132];
    __shared__ float s_b[16 * 132];
    int tid = threadIdx.x;
    #pragma unroll
    for (int i = 0; i < 8; ++i) {
        int idx = i * 256 + tid;
        int r = idx >> 5, c4 = (idx & 31) * 4;
        *reinterpret_cast<float4*>(&s_h[r * 132 + c4]) =
            *reinterpret_cast<const float4*>(&hs[((size_t)node * 64 + r) * 128 + c4]);
    }
    __syncthreads();
    int rg = tid >> 4, cg = tid & 15;
    int r0 = rg * 4;
    const float* W1 = t_w1 + (size_t)li * FF_ * 128;
    const float* b1 = t_b1 + (size_t)li * FF_;
    const float* W2 = t_w2 + (size_t)li * 128 * FF_;
    const float* b2 = t_b2 + (size_t)li * 128;
    float4 c2lo[4], c2hi[4];
    #pragma unroll
    for (int rr = 0; rr < 4; ++rr) { c2lo[rr] = f4zero(); c2hi[rr] = f4zero(); }

    for (int nt = 0; nt < 4; ++nt) {
        // GEMM1: f1[64][128] = s_h @ W1[nt*128..]^T
        float4 c1lo[4], c1hi[4];
        #pragma unroll
        for (int rr = 0; rr < 4; ++rr) { c1lo[rr] = f4zero(); c1hi[rr] = f4zero(); }
        for (int kci = 0; kci < 8; ++kci) {   // KC=16
            #pragma unroll
            for (int i = 0; i < 2; ++i) {
                int idx = i * 256 + tid;
                int jj = idx >> 2, k4 = (idx & 3) * 4;
                float4 w = *reinterpret_cast<const float4*>(&W1[(size_t)(nt * 128 + jj) * 128 + kci * 16 + k4]);
                s_b[(k4 + 0) * 132 + jj] = w.x; s_b[(k4 + 1) * 132 + jj] = w.y;
                s_b[(k4 + 2) * 132 + jj] = w.z; s_b[(k4 + 3) * 132 + jj] = w.w;
            }
            __syncthreads();
            #pragma unroll
            for (int k4 = 0; k4 < 4; ++k4) {
                float4 a4[4];
                #pragma unroll
                for (int rr = 0; rr < 4; ++rr)
                    a4[rr] = *reinterpret_cast<const float4*>(&s_h[(r0 + rr) * 132 + kci * 16 + k4 * 4]);
                #pragma unroll
                for (int jj = 0; jj < 4; ++jj) {
                    float4 blo = *reinterpret_cast<const float4*>(&s_b[(k4 * 4 + jj) * 132 + cg * 4]);
                    float4 bhi = *reinterpret_cast<const float4*>(&s_b[(k4 * 4 + jj) * 132 + 64 + cg * 4]);
                    #pragma unroll
                    for (int rr = 0; rr < 4; ++rr) {
                        float av = (jj == 0) ? a4[rr].x : (jj == 1) ? a4[rr].y : (jj == 2) ? a4[rr].z : a4[rr].w;
                        f4fma(c1lo[rr], av, blo);
                        f4fma(c1hi[rr], av, bhi);
                    }
                }
            }
            __syncthreads();
        }
        // bias + gelu -> s_f
        {
            float4 blo = *reinterpret_cast<const float4*>(&b1[nt * 128 + cg * 4]);
            float4 bhi = *reinterpret_cast<const float4*>(&b1[nt * 128 + 64 + cg * 4]);
            #pragma unroll
            for (int rr = 0; rr < 4; ++rr) {
                float4 lo = c1lo[rr], hi = c1hi[rr];
                lo.x = gelu_exact(lo.x + blo.x); lo.y = gelu_exact(lo.y + blo.y);
                lo.z = gelu_exact(lo.z + blo.z); lo.w = gelu_exact(lo.w + blo.w);
                hi.x = gelu_exact(hi.x + bhi.x); hi.y = gelu_exact(hi.y + bhi.y);
                hi.z = gelu_exact(hi.z + bhi.z); hi.w = gelu_exact(hi.w + bhi.w);
                *reinterpret_cast<float4*>(&s_f[(r0 + rr) * 132 + cg * 4]) = lo;
                *reinterpret_cast<float4*>(&s_f[(r0 + rr) * 132 + 64 + cg * 4]) = hi;
            }
        }
        __syncthreads();
        // GEMM2: acc2 += s_f @ W2[:, nt*128..]^T
        for (int kci = 0; kci < 8; ++kci) {
            #pragma unroll
            for (int i = 0; i < 2; ++i) {
                int idx = i * 256 + tid;
                int jj = idx >> 2, k4 = (idx & 3) * 4;
                float4 w = *reinterpret_cast<const float4*>(&W2[(size_t)jj * FF_ + nt * 128 + kci * 16 + k4]);
                s_b[(k4 + 0) * 132 + jj] = w.x; s_b[(k4 + 1) * 132 + jj] = w.y;
                s_b[(k4 + 2) * 132 + jj] = w.z; s_b[(k4 + 3) * 132 + jj] = w.w;
            }
            __syncthreads();
            #pragma unroll
            for (int k4 = 0; k4 < 4; ++k4) {
                float4 a4[4];
                #pragma unroll
                for (int rr = 0; rr < 4; ++rr)
                    a4[rr] = *reinterpret_cast<const float4*>(&s_f[(r0 + rr) * 132 + kci * 16 + k4 * 4]);
                #pragma unroll
                for (int jj = 0; jj < 4; ++jj) {
                    float4 blo = *reinterpret_cast<const float4*>(&s_b[(k4 * 4 + jj) * 132 + cg * 4]);
                    float4 bhi = *reinterpret_cast<const float4*>(&s_b[(k4 * 4 + jj) * 132 + 64 + cg * 4]);
                    #pragma unroll
                    for (int rr = 0; rr < 4; ++rr) {
                        float av = (jj == 0) ? a4[rr].x : (jj == 1) ? a4[rr].y : (jj == 2) ? a4[rr].z : a4[rr].w;
                        f4fma(c2lo[rr], av, blo);
                        f4fma(c2hi[rr], av, bhi);
                    }
                }
            }
            __syncthreads();
        }
    }
    // epilogue: bias + residual(s_h) + LN2 -> hs
    float4 bblo = *reinterpret_cast<const float4*>(&b2[cg * 4]);
    float4 bbhi = *reinterpret_cast<const float4*>(&b2[64 + cg * 4]);
    float4 glo = *reinterpret_cast<const float4*>(&ln_g[(size_t)li * 128 + cg * 4]);
    float4 ghi = *reinterpret_cast<const float4*>(&ln_g[(size_t)li * 128 + 64 + cg * 4]);
    float4 lblo = *reinterpret_cast<const float4*>(&ln_b[(size_t)li * 128 + cg * 4]);
    float4 lbhi = *reinterpret_cast<const float4*>(&ln_b[(size_t)li * 128 + 64 + cg * 4]);
    #pragma unroll
    for (int rr = 0; rr < 4; ++rr) {
        size_t row = (size_t)node * 64 + r0 + rr;
        float4 rlo = *reinterpret_cast<const float4*>(&s_h[(r0 + rr) * 132 + cg * 4]);
        float4 rhi = *reinterpret_cast<const float4*>(&s_h[(r0 + rr) * 132 + 64 + cg * 4]);
        float4 lo = c2lo[rr], hi = c2hi[rr];
        lo.x += bblo.x + rlo.x; lo.y += bblo.y + rlo.y; lo.z += bblo.z + rlo.z; lo.w += bblo.w + rlo.w;
        hi.x += bbhi.x + rhi.x; hi.y += bbhi.y + rhi.y; hi.z += bbhi.z + rhi.z; hi.w += bbhi.w + rhi.w;
        float s = lo.x + lo.y + lo.z + lo.w + hi.x + hi.y + hi.z + hi.w;
        s += __shfl_xor(s, 1); s += __shfl_xor(s, 2); s += __shfl_xor(s, 4); s += __shfl_xor(s, 8);
        float mean = s * (1.0f / 128.0f);
        float4 dlo = make_float4(lo.x - mean, lo.y - mean, lo.z - mean, lo.w - mean);
        float4 dhi = make_float4(hi.x - mean, hi.y - mean, hi.z - mean, hi.w - mean);
        float vx = dlo.x * dlo.x + dlo.y * dlo.y + dlo.z * dlo.z + dlo.w * dlo.w +
                   dhi.x * dhi.x + dhi.y * dhi.y + dhi.z * dhi.z + dhi.w * dhi.w;
        vx += __shfl_xor(vx, 1); vx += __shfl_xor(vx, 2); vx += __shfl_xor(vx, 4); vx += __shfl_xor(vx, 8);
        float rstd = rsqrtf(vx * (1.0f / 128.0f) + 1e-5f);
        float4 olo = make_float4(dlo.x * rstd * glo.x + lblo.x, dlo.y * rstd * glo.y + lblo.y,
                                 dlo.z * rstd * glo.z + lblo.z, dlo.w * rstd * glo.w + lblo.w);
        float4 ohi = make_float4(dhi.x * rstd * ghi.x + lbhi.x, dhi.y * rstd * ghi.y + lbhi.y,
                                 dhi.z * rstd * ghi.z + lbhi.z, dhi.w * rstd * ghi.w + lbhi.w);
        *reinterpret_cast<float4*>(&hs[row * 128 + cg * 4]) = olo;
        *reinterpret_cast<float4*>(&hs[row * 128 + 64 + cg * 4]) = ohi;
    }
}

// ---------------- final LN -> out ----------------

__global__ __launch_bounds__(256) void k_fln(const float* __restrict__ hs, float* __restrict__ out,
                                             const float* __restrict__ g, const float* __restrict__ b) {
    int row = blockIdx.x * 4 + (threadIdx.x >> 6);
    int l = threadIdx.x & 63;
    float v0 = hs[(size_t)row * H_ + l];
    float v1 = hs[(size_t)row * H_ + 64 + l];
    float s = v0 + v1;
    #pragma unroll
    for (int off = 32; off; off >>= 1) s += __shfl_xor(s, off);
    float mean = s * (1.0f / H_);
    float d0 = v0 - mean, d1 = v1 - mean;
    float vs = d0 * d0 + d1 * d1;
    #pragma unroll
    for (int off = 32; off; off >>= 1) vs += __shfl_xor(vs, off);
    float rstd = rsqrtf(vs * (1.0f / H_) + 1e-5f);
    out[(size_t)row * H_ + l] = d0 * rstd * g[l] + b[l];
    out[(size_t)row * H_ + 64 + l] = d1 * rstd * g[64 + l] + b[64 + l];
}

// ---------------- launch ----------------

extern "C" void kernel_launch(void* const* d_in, const int* in_sizes, int n_in,
                              void* d_out, int out_size, void* d_ws, size_t ws_size,
                              hipStream_t stream) {
    const float* x          = (const float*)d_in[0];
    const int*   edge_index = (const int*)d_in[1];
    const int*   edge_type  = (const int*)d_in[2];
    const int*   node_type  = (const int*)d_in[3];
    const float* W_in    = (const float*)d_in[6];
    const float* b_in    = (const float*)d_in[7];
    const float* s_in_w  = (const float*)d_in[8];
    const float* s_in_b  = (const float*)d_in[9];
    const float* s_out_w = (const float*)d_in[10];
    const float* s_out_b = (const float*)d_in[11];
    const float* ln_s_g  = (const float*)d_in[12];
    const float* ln_s_b  = (const float*)d_in[13];
    const float* t_in_w  = (const float*)d_in[14];
    const float* t_in_b  = (const float*)d_in[15];
    const float* t_out_w = (const float*)d_in[16];
    const float* t_out_b = (const float*)d_in[17];
    const float* t_ln1_g = (const float*)d_in[18];
    const float* t_ln1_b = (const float*)d_in[19];
    const float* t_w1    = (const float*)d_in[20];
    const float* t_b1    = (const float*)d_in[21];
    const float* t_w2    = (const float*)d_in[22];
    const float* t_b2    = (const float*)d_in[23];
    const float* t_ln2_g = (const float*)d_in[24];
    const float* t_ln2_b = (const float*)d_in[25];
    const float* fin_g   = (const float*)d_in[26];
    const float* fin_b   = (const float*)d_in[27];
    float* out = (float*)d_out;

    // workspace layout (floats)
    float* h     = (float*)d_ws;                       // N*H = 8388608
    float* h_new = h + (size_t)N_ * H_;                // 8388608
    float* qkv   = h_new + (size_t)N_ * H_;            // E*384 = 11520000
    int* sorted  = (int*)(qkv + (size_t)E_ * 384);     // E
    int* gpos    = sorted + E_;                        // E
    int* gedge   = gpos + E_;                          // E
    int* cnt     = gedge + E_;                         // 64
    int* offs    = cnt + 64;                           // 64
    int* curs    = offs + 64;                          // 64
    int* nd64    = curs + 64;                          // 16
    int2* desc64 = (int2*)(nd64 + 16);                 // 544 int2

    // temporal chunk buffers (alias spatial regions, used after spatial completes)
    float* qc = qkv;                                   // CH*64*128 = 4194304
    float* kc = qkv + (size_t)CH_ * 64 * 128;          // 4194304
    float* vc = h_new;                                 // 4194304

    k_zero_cnt<<<1, 64, 0, stream>>>(cnt);
    k_hist<<<(E_ + 255) / 256, 256, 0, stream>>>(edge_index, edge_type, node_type, gedge, cnt);
    k_scan<<<1, 1, 0, stream>>>(cnt, offs, curs);
    k_scatter<<<(E_ + 255) / 256, 256, 0, stream>>>(gedge, curs, sorted, gpos);
    k_desc<<<1, 1, 0, stream>>>(offs, desc64, nd64);

    k_inproj<<<N_, 128, 0, stream>>>(x, node_type, W_in, b_in, h);

    for (int li = 0; li < L_; ++li) {
        k_zero<<<2048, 256, 0, stream>>>(h_new, N_ * H_);
        k_sqkv_gemm<<<dim3(544, 3), 256, 0, stream>>>(h, s_in_w, s_in_b, sorted, offs, edge_index,
                                                      desc64, nd64, qkv, li);
        k_gattn<<<544, 128, 0, stream>>>(qkv, sorted, offs, edge_index, desc64, nd64,
                                         s_out_w, s_out_b, h_new, li);
        k_lngelu<<<N_, 64, 0, stream>>>(h_new, h, ln_s_g, ln_s_b, li);
    }

    // temporal: hs = h + PE (in place)
    k_peadd<<<2048, 256, 0, stream>>>(h);
    for (int li = 0; li < TL_; ++li) {
        for (int c = 0; c < NB_ / CH_; ++c) {
            int c0 = c * CH_;
            k_tqkv<<<dim3(CH_, 3), 256, 0, stream>>>(h, t_in_w, t_in_b, qc, kc, vc, li, c0);
            k_tattn<<<dim3(CH_, NH_), 64, 0, stream>>>(qc, kc, vc);
            k_toutln<<<CH_, 256, 0, stream>>>(qc, h, t_out_w, t_out_b, t_ln1_g, t_ln1_b, li, c0);
        }
        k_tff<<<NB_, 256, 0, stream>>>(h, t_w1, t_b1, t_w2, t_b2, t_ln2_g, t_ln2_b, li);
    }
    k_fln<<<N_ / 4, 256, 0, stream>>>(h, out, fin_g, fin_b);
}

// Round 5
// 2371.912 us; speedup vs baseline: 1.8097x; 1.8097x over previous
//
#include <hip/hip_runtime.h>
#include <hip/hip_bf16.h>
#include <math.h>

// Problem constants (fixed by reference)
#define N_   65536
#define F_   64
#define H_   128
#define E_   30000
#define NT_  5
#define ET_  10
#define NG_  50
#define L_   3
#define TL_  2
#define NH_  4
#define DH_  32
#define NB_  1024
#define TT_  64
#define FF_  512
#define CH_  512    // temporal node chunk

#define SCALE_ 0.17677669529663687f   // 1/sqrt(32)

__device__ __forceinline__ float gelu_exact(float x) {
    return 0.5f * x * (1.0f + erff(x * 0.70710678118654752f));
}
__device__ __forceinline__ void f4fma(float4& a, float s, const float4& b) {
    a.x += s * b.x; a.y += s * b.y; a.z += s * b.z; a.w += s * b.w;
}
__device__ __forceinline__ void f4scale(float4& a, float s) {
    a.x *= s; a.y *= s; a.z *= s; a.w *= s;
}
__device__ __forceinline__ float4 f4zero() { return make_float4(0.f, 0.f, 0.f, 0.f); }

// ---------------- grouping ----------------

__global__ void k_zero_cnt(int* cnt) {
    if (threadIdx.x < NG_) cnt[threadIdx.x] = 0;
}

__global__ void k_hist(const int* __restrict__ edge_index, const int* __restrict__ edge_type,
                       const int* __restrict__ node_type, int* __restrict__ gedge, int* __restrict__ cnt) {
    int e = blockIdx.x * blockDim.x + threadIdx.x;
    if (e >= E_) return;
    int dn = edge_index[E_ + e];
    int g = edge_type[e] * NT_ + node_type[dn];
    gedge[e] = g;
    atomicAdd(&cnt[g], 1);
}

__global__ void k_scan(const int* __restrict__ cnt, int* __restrict__ offs, int* __restrict__ curs) {
    if (threadIdx.x == 0 && blockIdx.x == 0) {
        int acc = 0;
        for (int g = 0; g < NG_; ++g) { offs[g] = acc; curs[g] = acc; acc += cnt[g]; }
        offs[NG_] = acc;
    }
}

__global__ void k_scatter(const int* __restrict__ gedge, int* __restrict__ curs,
                          int* __restrict__ sorted, int* __restrict__ gpos) {
    int e = blockIdx.x * blockDim.x + threadIdx.x;
    if (e >= E_) return;
    int g = gedge[e];
    int pos = atomicAdd(&curs[g], 1);
    sorted[pos] = e;
    gpos[pos] = g;
}

// descriptor lists: 64-edge tiles (qkv gemm + attention)
__global__ void k_desc(const int* __restrict__ offs, int2* __restrict__ desc64, int* __restrict__ nd64) {
    if (threadIdx.x || blockIdx.x) return;
    int n64 = 0;
    for (int g = 0; g < NG_; ++g) {
        int sz = offs[g + 1] - offs[g];
        for (int qs = 0; qs < sz; qs += 64) desc64[n64++] = make_int2(g, qs);
    }
    nd64[0] = n64;
}

// ---------------- input projection ----------------

__global__ void k_inproj(const float* __restrict__ x, const int* __restrict__ node_type,
                         const float* __restrict__ W_in, const float* __restrict__ b_in,
                         float* __restrict__ h) {
    int n = blockIdx.x;
    int j = threadIdx.x;  // 0..127
    __shared__ float sx[F_];
    if (j < F_) sx[j] = x[(size_t)n * F_ + j];
    __syncthreads();
    int nt = node_type[n];
    const float* W = W_in + (size_t)nt * F_ * H_;
    float acc = b_in[(size_t)nt * H_ + j];
    #pragma unroll 8
    for (int f = 0; f < F_; ++f) acc += sx[f] * W[(size_t)f * H_ + j];
    h[(size_t)n * H_ + j] = acc;
}

__global__ void k_zero(float* __restrict__ p, int n) {
    int i = blockIdx.x * blockDim.x + threadIdx.x;
    int stride = gridDim.x * blockDim.x;
    for (; i < n; i += stride) p[i] = 0.0f;
}

// ---------------- spatial qkv projection: tiled GEMM over 64-edge tiles ----------------
// grid = (tiles, 3); y: 0=q (dst rows), 1=k, 2=v (src rows)

__global__ __launch_bounds__(256) void k_sqkv_gemm(
    const float* __restrict__ h, const float* __restrict__ s_in_w, const float* __restrict__ s_in_b,
    const int* __restrict__ sorted, const int* __restrict__ offs, const int* __restrict__ edge_index,
    const int2* __restrict__ desc64, const int* __restrict__ nd64,
    float* __restrict__ qkv, int li) {
    int bx = blockIdx.x;
    if (bx >= nd64[0]) return;
    int2 dd = desc64[bx];
    int g = dd.x, qs = dd.y;
    int qbase = offs[g] + qs;
    int qcnt = min(64, offs[g + 1] - qbase);
    int et = g / NT_;
    int nt = blockIdx.y;
    __shared__ float s_a[64 * 132];
    __shared__ float s_b[32 * 132];
    int tid = threadIdx.x;
    // gather 64 input rows (dst for q, src for k/v)
    #pragma unroll
    for (int i = 0; i < 8; ++i) {
        int idx = i * 256 + tid;
        int r = idx >> 5, c4 = (idx & 31) * 4;
        int p = qbase + min(r, qcnt - 1);
        int e = sorted[p];
        int node = (nt == 0) ? edge_index[E_ + e] : edge_index[e];
        *reinterpret_cast<float4*>(&s_a[r * 132 + c4]) =
            *reinterpret_cast<const float4*>(&h[(size_t)node * H_ + c4]);
    }
    const float* B = s_in_w + ((size_t)(li * ET_ + et) * 3 * H_ + nt * H_) * H_;
    const float* bi = s_in_b + (size_t)(li * ET_ + et) * 3 * H_ + nt * H_;
    int rg = tid >> 4, cg = tid & 15;
    int r0 = rg * 4;
    float4 alo[4], ahi[4];
    #pragma unroll
    for (int rr = 0; rr < 4; ++rr) { alo[rr] = f4zero(); ahi[rr] = f4zero(); }
    for (int kci = 0; kci < 4; ++kci) {
        __syncthreads();
        #pragma unroll
        for (int i = 0; i < 4; ++i) {
            int idx = i * 256 + tid;
            int jj = idx >> 3, k4 = (idx & 7) * 4;
            float4 w = *reinterpret_cast<const float4*>(&B[(size_t)jj * H_ + kci * 32 + k4]);
            s_b[(k4 + 0) * 132 + jj] = w.x; s_b[(k4 + 1) * 132 + jj] = w.y;
            s_b[(k4 + 2) * 132 + jj] = w.z; s_b[(k4 + 3) * 132 + jj] = w.w;
        }
        __syncthreads();
        #pragma unroll
        for (int k4 = 0; k4 < 8; ++k4) {
            float4 a4[4];
            #pragma unroll
            for (int rr = 0; rr < 4; ++rr)
                a4[rr] = *reinterpret_cast<const float4*>(&s_a[(r0 + rr) * 132 + kci * 32 + k4 * 4]);
            #pragma unroll
            for (int jj = 0; jj < 4; ++jj) {
                float4 blo = *reinterpret_cast<const float4*>(&s_b[(k4 * 4 + jj) * 132 + cg * 4]);
                float4 bhi = *reinterpret_cast<const float4*>(&s_b[(k4 * 4 + jj) * 132 + 64 + cg * 4]);
                #pragma unroll
                for (int rr = 0; rr < 4; ++rr) {
                    float av = (jj == 0) ? a4[rr].x : (jj == 1) ? a4[rr].y : (jj == 2) ? a4[rr].z : a4[rr].w;
                    f4fma(alo[rr], av, blo);
                    f4fma(ahi[rr], av, bhi);
                }
            }
        }
    }
    float4 blo = *reinterpret_cast<const float4*>(&bi[cg * 4]);
    float4 bhi = *reinterpret_cast<const float4*>(&bi[64 + cg * 4]);
    #pragma unroll
    for (int rr = 0; rr < 4; ++rr) {
        int row = r0 + rr;
        if (row < qcnt) {
            float* op = qkv + (size_t)(qbase + row) * 384 + nt * H_;
            float4 lo = alo[rr], hi = ahi[rr];
            lo.x += blo.x; lo.y += blo.y; lo.z += blo.z; lo.w += blo.w;
            hi.x += bhi.x; hi.y += bhi.y; hi.z += bhi.z; hi.w += bhi.w;
            *reinterpret_cast<float4*>(op + cg * 4) = lo;
            *reinterpret_cast<float4*>(op + 64 + cg * 4) = hi;
        }
    }
}

// ---------------- grouped spatial attention + out-proj + scatter ----------------
// block = one (group, 64-query tile); 256 threads = 4 heads x 64 queries, 1 query/thread

__global__ __launch_bounds__(256, 2) void k_gattn(
    const float* __restrict__ qkv, const int* __restrict__ sorted,
    const int* __restrict__ offs, const int* __restrict__ edge_index,
    const int2* __restrict__ desc, const int* __restrict__ ndesc,
    const float* __restrict__ s_out_w, const float* __restrict__ s_out_b,
    float* __restrict__ h_new, int li) {
    int bx = blockIdx.x;
    if (bx >= ndesc[0]) return;
    int2 dd = desc[bx];
    int g = dd.x, qs = dd.y;
    int start = offs[g], end = offs[g + 1];
    int qbase = start + qs;
    int qcnt = min(64, end - qbase);
    int et = g / NT_;
    // union buffer: during attention = s_k[32*132] ++ s_v[32*132]; after = s_o[64*132]
    __shared__ float s_buf[64 * 132];
    __shared__ int s_dn[64];
    float* s_k = s_buf;
    float* s_v = s_buf + 32 * 132;
    float* s_o = s_buf;
    int tid = threadIdx.x;
    int head = tid >> 6, qi = tid & 63;   // wave = one head, 64 queries

    if (tid < 64) {
        int p = qbase + min(tid, qcnt - 1);
        s_dn[tid] = edge_index[E_ + sorted[p]];
    }

    int p0 = qbase + min(qi, qcnt - 1);
    float4 q[8];
    {
        const float4* qr = reinterpret_cast<const float4*>(&qkv[(size_t)p0 * 384 + head * DH_]);
        #pragma unroll
        for (int i = 0; i < 8; ++i) q[i] = qr[i];
    }
    float m = -1e30f, ssum = 0.0f;
    float4 o[8];
    #pragma unroll
    for (int i = 0; i < 8; ++i) o[i] = f4zero();

    int nkt = (end - start + 31) >> 5;
    for (int kt = 0; kt < nkt; ++kt) {
        int kb = start + kt * 32;
        int kcnt = min(32, end - kb);
        __syncthreads();
        // stage k,v: 32 rows x 256 floats = 2048 float4, 8 per thread
        #pragma unroll
        for (int i = 0; i < 8; ++i) {
            int idx = i * 256 + tid;
            int row = idx >> 6, c4 = idx & 63;
            if (row < kcnt) {
                float4 w = *reinterpret_cast<const float4*>(&qkv[(size_t)(kb + row) * 384 + 128 + c4 * 4]);
                int c = c4 * 4;
                float* dp = (c < 128) ? &s_k[row * 132 + c] : &s_v[row * 132 + (c - 128)];
                *reinterpret_cast<float4*>(dp) = w;
            }
        }
        __syncthreads();
        if (kcnt == 32) {
            // single pass: scores in statically-indexed registers
            float sc[32];
            float tmax = -1e30f;
            #pragma unroll
            for (int t2 = 0; t2 < 32; ++t2) {
                const float4* kr = reinterpret_cast<const float4*>(&s_k[t2 * 132 + head * DH_]);
                float s0 = 0, s1 = 0, s2 = 0, s3 = 0;
                #pragma unroll
                for (int i = 0; i < 8; ++i) {
                    float4 kk = kr[i];
                    s0 += q[i].x * kk.x; s1 += q[i].y * kk.y; s2 += q[i].z * kk.z; s3 += q[i].w * kk.w;
                }
                float dot = ((s0 + s1) + (s2 + s3)) * SCALE_;
                sc[t2] = dot;
                tmax = fmaxf(tmax, dot);
            }
            float mn = fmaxf(m, tmax);
            float f = __expf(m - mn);
            ssum *= f;
            #pragma unroll
            for (int i = 0; i < 8; ++i) f4scale(o[i], f);
            #pragma unroll
            for (int t2 = 0; t2 < 32; ++t2) {
                float p = __expf(sc[t2] - mn);
                ssum += p;
                const float4* vr = reinterpret_cast<const float4*>(&s_v[t2 * 132 + head * DH_]);
                #pragma unroll
                for (int i = 0; i < 8; ++i) f4fma(o[i], p, vr[i]);
            }
            m = mn;
        } else {
            // tail: two-pass recompute
            float tmax = -1e30f;
            for (int t2 = 0; t2 < kcnt; ++t2) {
                const float4* kr = reinterpret_cast<const float4*>(&s_k[t2 * 132 + head * DH_]);
                float s0 = 0, s1 = 0, s2 = 0, s3 = 0;
                #pragma unroll
                for (int i = 0; i < 8; ++i) {
                    float4 kk = kr[i];
                    s0 += q[i].x * kk.x; s1 += q[i].y * kk.y; s2 += q[i].z * kk.z; s3 += q[i].w * kk.w;
                }
                tmax = fmaxf(tmax, ((s0 + s1) + (s2 + s3)) * SCALE_);
            }
            float mn = fmaxf(m, tmax);
            float f = __expf(m - mn);
            ssum *= f;
            #pragma unroll
            for (int i = 0; i < 8; ++i) f4scale(o[i], f);
            for (int t2 = 0; t2 < kcnt; ++t2) {
                const float4* kr = reinterpret_cast<const float4*>(&s_k[t2 * 132 + head * DH_]);
                float s0 = 0, s1 = 0, s2 = 0, s3 = 0;
                #pragma unroll
                for (int i = 0; i < 8; ++i) {
                    float4 kk = kr[i];
                    s0 += q[i].x * kk.x; s1 += q[i].y * kk.y; s2 += q[i].z * kk.z; s3 += q[i].w * kk.w;
                }
                float p = __expf(((s0 + s1) + (s2 + s3)) * SCALE_ - mn);
                ssum += p;
                const float4* vr = reinterpret_cast<const float4*>(&s_v[t2 * 132 + head * DH_]);
                #pragma unroll
                for (int i = 0; i < 8; ++i) f4fma(o[i], p, vr[i]);
            }
            m = mn;
        }
    }
    __syncthreads();   // all reads of s_k/s_v done before s_o overwrites the buffer
    float inv = 1.0f / ssum;
    if (qi < qcnt) {
        #pragma unroll
        for (int i = 0; i < 8; ++i) {
            float4 t = o[i]; f4scale(t, inv);
            *reinterpret_cast<float4*>(&s_o[qi * 132 + head * DH_ + i * 4]) = t;
        }
    }
    __syncthreads();
    // out-projection: thread = (col j, query-half); 32 queries per thread
    {
        int j = tid & 127, half = tid >> 7;
        const float* Wo = s_out_w + ((size_t)(li * ET_ + et) * H_ + j) * H_;
        float bo = s_out_b[(size_t)(li * ET_ + et) * H_ + j];
        float acc[32];
        #pragma unroll
        for (int qq = 0; qq < 32; ++qq) acc[qq] = bo;
        #pragma unroll 8
        for (int k4 = 0; k4 < 32; ++k4) {
            float4 w = *reinterpret_cast<const float4*>(&Wo[k4 * 4]);
            #pragma unroll
            for (int qq = 0; qq < 32; ++qq) {
                float4 ov = *reinterpret_cast<const float4*>(&s_o[(half * 32 + qq) * 132 + k4 * 4]);
                acc[qq] += w.x * ov.x + w.y * ov.y + w.z * ov.z + w.w * ov.w;
            }
        }
        #pragma unroll
        for (int qq = 0; qq < 32; ++qq) {
            int qrow = half * 32 + qq;
            if (qrow < qcnt) {
                atomicAdd(&h_new[(size_t)s_dn[qrow] * H_ + j], acc[qq]);
            }
        }
    }
}

// ---------------- LN + exact GELU + residual (spatial) ----------------

__global__ void k_lngelu(const float* __restrict__ h_new, float* __restrict__ h,
                         const float* __restrict__ ln_g, const float* __restrict__ ln_b, int li) {
    int n = blockIdx.x;
    int l = threadIdx.x;  // 0..63
    float v0 = h_new[(size_t)n * H_ + l];
    float v1 = h_new[(size_t)n * H_ + 64 + l];
    float s = v0 + v1;
    #pragma unroll
    for (int off = 32; off; off >>= 1) s += __shfl_xor(s, off);
    float mean = s * (1.0f / H_);
    float d0 = v0 - mean, d1 = v1 - mean;
    float vs = d0 * d0 + d1 * d1;
    #pragma unroll
    for (int off = 32; off; off >>= 1) vs += __shfl_xor(vs, off);
    float rstd = rsqrtf(vs * (1.0f / H_) + 1e-5f);
    const float* gg = ln_g + (size_t)li * H_;
    const float* bb = ln_b + (size_t)li * H_;
    float t0 = gelu_exact(d0 * rstd * gg[l] + bb[l]);
    float t1 = gelu_exact(d1 * rstd * gg[64 + l] + bb[64 + l]);
    size_t o = (size_t)n * H_;
    if (li == 0) { h[o + l] = t0; h[o + 64 + l] = t1; }
    else         { h[o + l] += t0; h[o + 64 + l] += t1; }
}

// ---------------- temporal: positional encoding add (in place on h) ----------------

__global__ void k_peadd(float* __restrict__ h) {
    int i = blockIdx.x * blockDim.x + threadIdx.x;
    int stride = gridDim.x * blockDim.x;
    for (; i < N_ * H_; i += stride) {
        int j = i & 127;
        int t = (i >> 7) & 63;
        float dv = __expf((float)(j & ~1) * (-0.0719557841560639f));
        float ang = (float)t * dv;
        float pe = (j & 1) ? cosf(ang) : sinf(ang);
        h[i] += pe;
    }
}

// ---------------- temporal qkv GEMM: block = (node-in-chunk, {q,k,v}) ----------------

__global__ __launch_bounds__(256) void k_tqkv(const float* __restrict__ hs,
                                              const float* __restrict__ t_in_w, const float* __restrict__ t_in_b,
                                              float* __restrict__ qc, float* __restrict__ kc, float* __restrict__ vc,
                                              int li, int c0) {
    int nb = blockIdx.x;        // node in chunk
    int nt = blockIdx.y;        // 0=q 1=k 2=v
    int node = c0 + nb;
    __shared__ float s_a[64 * 132];
    __shared__ float s_b[32 * 132];
    int tid = threadIdx.x;
    // stage A: node's 64x128 hs tile
    #pragma unroll
    for (int i = 0; i < 8; ++i) {
        int idx = i * 256 + tid;
        int r = idx >> 5, c4 = (idx & 31) * 4;
        *reinterpret_cast<float4*>(&s_a[r * 132 + c4]) =
            *reinterpret_cast<const float4*>(&hs[((size_t)node * 64 + r) * 128 + c4]);
    }
    const float* B = t_in_w + ((size_t)li * 384 + nt * 128) * 128;
    const float* bi = t_in_b + (size_t)li * 384 + nt * 128;
    int rg = tid >> 4, cg = tid & 15;
    int r0 = rg * 4;
    float4 alo[4], ahi[4];
    #pragma unroll
    for (int rr = 0; rr < 4; ++rr) { alo[rr] = f4zero(); ahi[rr] = f4zero(); }
    for (int kci = 0; kci < 4; ++kci) {
        __syncthreads();
        #pragma unroll
        for (int i = 0; i < 4; ++i) {
            int idx = i * 256 + tid;
            int jj = idx >> 3, k4 = (idx & 7) * 4;
            float4 w = *reinterpret_cast<const float4*>(&B[(size_t)jj * 128 + kci * 32 + k4]);
            s_b[(k4 + 0) * 132 + jj] = w.x; s_b[(k4 + 1) * 132 + jj] = w.y;
            s_b[(k4 + 2) * 132 + jj] = w.z; s_b[(k4 + 3) * 132 + jj] = w.w;
        }
        __syncthreads();
        #pragma unroll
        for (int k4 = 0; k4 < 8; ++k4) {
            float4 a4[4];
            #pragma unroll
            for (int rr = 0; rr < 4; ++rr)
                a4[rr] = *reinterpret_cast<const float4*>(&s_a[(r0 + rr) * 132 + kci * 32 + k4 * 4]);
            #pragma unroll
            for (int jj = 0; jj < 4; ++jj) {
                float4 blo = *reinterpret_cast<const float4*>(&s_b[(k4 * 4 + jj) * 132 + cg * 4]);
                float4 bhi = *reinterpret_cast<const float4*>(&s_b[(k4 * 4 + jj) * 132 + 64 + cg * 4]);
                #pragma unroll
                for (int rr = 0; rr < 4; ++rr) {
                    float av = (jj == 0) ? a4[rr].x : (jj == 1) ? a4[rr].y : (jj == 2) ? a4[rr].z : a4[rr].w;
                    f4fma(alo[rr], av, blo);
                    f4fma(ahi[rr], av, bhi);
                }
            }
        }
    }
    float* dst = (nt == 0) ? qc : (nt == 1) ? kc : vc;
    float sc = (nt == 0) ? SCALE_ : 1.0f;
    float4 blo = *reinterpret_cast<const float4*>(&bi[cg * 4]);
    float4 bhi = *reinterpret_cast<const float4*>(&bi[64 + cg * 4]);
    #pragma unroll
    for (int rr = 0; rr < 4; ++rr) {
        float4 lo = alo[rr], hi = ahi[rr];
        lo.x = (lo.x + blo.x) * sc; lo.y = (lo.y + blo.y) * sc; lo.z = (lo.z + blo.z) * sc; lo.w = (lo.w + blo.w) * sc;
        hi.x = (hi.x + bhi.x) * sc; hi.y = (hi.y + bhi.y) * sc; hi.z = (hi.z + bhi.z) * sc; hi.w = (hi.w + bhi.w) * sc;
        size_t row = (size_t)nb * 64 + r0 + rr;
        *reinterpret_cast<float4*>(&dst[row * 128 + cg * 4]) = lo;
        *reinterpret_cast<float4*>(&dst[row * 128 + 64 + cg * 4]) = hi;
    }
}

// ---------------- temporal attention: block = (node-in-chunk, head), 64 threads ----------------

__global__ __launch_bounds__(64) void k_tattn(float* __restrict__ qc, const float* __restrict__ kc,
                                              const float* __restrict__ vc) {
    int nb = blockIdx.x, head = blockIdx.y;
    __shared__ float s_k[64 * 36];
    __shared__ float s_v[64 * 36];
    int t = threadIdx.x;
    #pragma unroll
    for (int i = 0; i < 8; ++i) {
        int idx = i * 64 + t;
        int row = idx >> 3, d4 = (idx & 7) * 4;
        *reinterpret_cast<float4*>(&s_k[row * 36 + d4]) =
            *reinterpret_cast<const float4*>(&kc[((size_t)nb * 64 + row) * 128 + head * DH_ + d4]);
        *reinterpret_cast<float4*>(&s_v[row * 36 + d4]) =
            *reinterpret_cast<const float4*>(&vc[((size_t)nb * 64 + row) * 128 + head * DH_ + d4]);
    }
    float4 q[8];
    {
        const float4* qr = reinterpret_cast<const float4*>(&qc[((size_t)nb * 64 + t) * 128 + head * DH_]);
        #pragma unroll
        for (int i = 0; i < 8; ++i) q[i] = qr[i];
    }
    __syncthreads();
    // pass 1: max
    float m = -1e30f;
    for (int t2 = 0; t2 < 64; ++t2) {
        const float4* kr = reinterpret_cast<const float4*>(&s_k[t2 * 36]);
        float s0 = 0, s1 = 0, s2 = 0, s3 = 0;
        #pragma unroll
        for (int i = 0; i < 8; ++i) {
            float4 kk = kr[i];
            s0 += q[i].x * kk.x; s1 += q[i].y * kk.y; s2 += q[i].z * kk.z; s3 += q[i].w * kk.w;
        }
        m = fmaxf(m, (s0 + s1) + (s2 + s3));
    }
    // pass 2: exp + PV
    float ssum = 0.0f;
    float4 o[8];
    #pragma unroll
    for (int i = 0; i < 8; ++i) o[i] = f4zero();
    for (int t2 = 0; t2 < 64; ++t2) {
        const float4* kr = reinterpret_cast<const float4*>(&s_k[t2 * 36]);
        float s0 = 0, s1 = 0, s2 = 0, s3 = 0;
        #pragma unroll
        for (int i = 0; i < 8; ++i) {
            float4 kk = kr[i];
            s0 += q[i].x * kk.x; s1 += q[i].y * kk.y; s2 += q[i].z * kk.z; s3 += q[i].w * kk.w;
        }
        float p = __expf((s0 + s1) + (s2 + s3) - m);
        ssum += p;
        const float4* vr = reinterpret_cast<const float4*>(&s_v[t2 * 36]);
        #pragma unroll
        for (int i = 0; i < 8; ++i) f4fma(o[i], p, vr[i]);
    }
    float inv = 1.0f / ssum;
    float4* orow = reinterpret_cast<float4*>(&qc[((size_t)nb * 64 + t) * 128 + head * DH_]);
    #pragma unroll
    for (int i = 0; i < 8; ++i) { float4 v = o[i]; f4scale(v, inv); orow[i] = v; }
}

// ---------------- temporal out-proj + residual + LN1 ----------------

__global__ __launch_bounds__(256) void k_toutln(const float* __restrict__ oc, float* __restrict__ hs,
                                                const float* __restrict__ t_out_w, const float* __restrict__ t_out_b,
                                                const float* __restrict__ ln_g, const float* __restrict__ ln_b,
                                                int li, int c0) {
    int nb = blockIdx.x;
    int node = c0 + nb;
    __shared__ float s_a[64 * 132];
    __shared__ float s_b[32 * 132];
    int tid = threadIdx.x;
    #pragma unroll
    for (int i = 0; i < 8; ++i) {
        int idx = i * 256 + tid;
        int r = idx >> 5, c4 = (idx & 31) * 4;
        *reinterpret_cast<float4*>(&s_a[r * 132 + c4]) =
            *reinterpret_cast<const float4*>(&oc[((size_t)nb * 64 + r) * 128 + c4]);
    }
    const float* B = t_out_w + (size_t)li * 128 * 128;
    const float* bo = t_out_b + (size_t)li * 128;
    int rg = tid >> 4, cg = tid & 15;
    int r0 = rg * 4;
    float4 alo[4], ahi[4];
    #pragma unroll
    for (int rr = 0; rr < 4; ++rr) { alo[rr] = f4zero(); ahi[rr] = f4zero(); }
    for (int kci = 0; kci < 4; ++kci) {
        __syncthreads();
        #pragma unroll
        for (int i = 0; i < 4; ++i) {
            int idx = i * 256 + tid;
            int jj = idx >> 3, k4 = (idx & 7) * 4;
            float4 w = *reinterpret_cast<const float4*>(&B[(size_t)jj * 128 + kci * 32 + k4]);
            s_b[(k4 + 0) * 132 + jj] = w.x; s_b[(k4 + 1) * 132 + jj] = w.y;
            s_b[(k4 + 2) * 132 + jj] = w.z; s_b[(k4 + 3) * 132 + jj] = w.w;
        }
        __syncthreads();
        #pragma unroll
        for (int k4 = 0; k4 < 8; ++k4) {
            float4 a4[4];
            #pragma unroll
            for (int rr = 0; rr < 4; ++rr)
                a4[rr] = *reinterpret_cast<const float4*>(&s_a[(r0 + rr) * 132 + kci * 32 + k4 * 4]);
            #pragma unroll
            for (int jj = 0; jj < 4; ++jj) {
                float4 blo = *reinterpret_cast<const float4*>(&s_b[(k4 * 4 + jj) * 132 + cg * 4]);
                float4 bhi = *reinterpret_cast<const float4*>(&s_b[(k4 * 4 + jj) * 132 + 64 + cg * 4]);
                #pragma unroll
                for (int rr = 0; rr < 4; ++rr) {
                    float av = (jj == 0) ? a4[rr].x : (jj == 1) ? a4[rr].y : (jj == 2) ? a4[rr].z : a4[rr].w;
                    f4fma(alo[rr], av, blo);
                    f4fma(ahi[rr], av, bhi);
                }
            }
        }
    }
    float4 bblo = *reinterpret_cast<const float4*>(&bo[cg * 4]);
    float4 bbhi = *reinterpret_cast<const float4*>(&bo[64 + cg * 4]);
    float4 glo = *reinterpret_cast<const float4*>(&ln_g[(size_t)li * 128 + cg * 4]);
    float4 ghi = *reinterpret_cast<const float4*>(&ln_g[(size_t)li * 128 + 64 + cg * 4]);
    float4 lblo = *reinterpret_cast<const float4*>(&ln_b[(size_t)li * 128 + cg * 4]);
    float4 lbhi = *reinterpret_cast<const float4*>(&ln_b[(size_t)li * 128 + 64 + cg * 4]);
    #pragma unroll
    for (int rr = 0; rr < 4; ++rr) {
        size_t row = (size_t)node * 64 + r0 + rr;
        float4 rlo = *reinterpret_cast<const float4*>(&hs[row * 128 + cg * 4]);
        float4 rhi = *reinterpret_cast<const float4*>(&hs[row * 128 + 64 + cg * 4]);
        float4 lo = alo[rr], hi = ahi[rr];
        lo.x += bblo.x + rlo.x; lo.y += bblo.y + rlo.y; lo.z += bblo.z + rlo.z; lo.w += bblo.w + rlo.w;
        hi.x += bbhi.x + rhi.x; hi.y += bbhi.y + rhi.y; hi.z += bbhi.z + rhi.z; hi.w += bbhi.w + rhi.w;
        float s = lo.x + lo.y + lo.z + lo.w + hi.x + hi.y + hi.z + hi.w;
        s += __shfl_xor(s, 1); s += __shfl_xor(s, 2); s += __shfl_xor(s, 4); s += __shfl_xor(s, 8);
        float mean = s * (1.0f / 128.0f);
        float4 dlo = make_float4(lo.x - mean, lo.y - mean, lo.z - mean, lo.w - mean);
        float4 dhi = make_float4(hi.x - mean, hi.y - mean, hi.z - mean, hi.w - mean);
        float vx = dlo.x * dlo.x + dlo.y * dlo.y + dlo.z * dlo.z + dlo.w * dlo.w +
                   dhi.x * dhi.x + dhi.y * dhi.y + dhi.z * dhi.z + dhi.w * dhi.w;
        vx += __shfl_xor(vx, 1); vx += __shfl_xor(vx, 2); vx += __shfl_xor(vx, 4); vx += __shfl_xor(vx, 8);
        float rstd = rsqrtf(vx * (1.0f / 128.0f) + 1e-5f);
        float4 olo = make_float4(dlo.x * rstd * glo.x + lblo.x, dlo.y * rstd * glo.y + lblo.y,
                                 dlo.z * rstd * glo.z + lblo.z, dlo.w * rstd * glo.w + lblo.w);
        float4 ohi = make_float4(dhi.x * rstd * ghi.x + lbhi.x, dhi.y * rstd * ghi.y + lbhi.y,
                                 dhi.z * rstd * ghi.z + lbhi.z, dhi.w * rstd * ghi.w + lbhi.w);
        *reinterpret_cast<float4*>(&hs[row * 128 + cg * 4]) = olo;
        *reinterpret_cast<float4*>(&hs[row * 128 + 64 + cg * 4]) = ohi;
    }
}

// ---------------- temporal fused FF (FF1+gelu+FF2) + residual + LN2 ----------------

__global__ __launch_bounds__(256) void k_tff(float* __restrict__ hs,
                                             const float* __restrict__ t_w1, const float* __restrict__ t_b1,
                                             const float* __restrict__ t_w2, const float* __restrict__ t_b2,
                                             const float* __restrict__ ln_g, const float* __restrict__ ln_b,
                                             int li) {
    int node = blockIdx.x;
    __shared__ float s_h[64 * 132];
    __shared__ float s_f[64 * 132];
    __shared__ float s_b[16 * 132];
    int tid = threadIdx.x;
    #pragma unroll
    for (int i = 0; i < 8; ++i) {
        int idx = i * 256 + tid;
        int r = idx >> 5, c4 = (idx & 31) * 4;
        *reinterpret_cast<float4*>(&s_h[r * 132 + c4]) =
            *reinterpret_cast<const float4*>(&hs[((size_t)node * 64 + r) * 128 + c4]);
    }
    __syncthreads();
    int rg = tid >> 4, cg = tid & 15;
    int r0 = rg * 4;
    const float* W1 = t_w1 + (size_t)li * FF_ * 128;
    const float* b1 = t_b1 + (size_t)li * FF_;
    const float* W2 = t_w2 + (size_t)li * 128 * FF_;
    const float* b2 = t_b2 + (size_t)li * 128;
    float4 c2lo[4], c2hi[4];
    #pragma unroll
    for (int rr = 0; rr < 4; ++rr) { c2lo[rr] = f4zero(); c2hi[rr] = f4zero(); }

    for (int nt = 0; nt < 4; ++nt) {
        // GEMM1: f1[64][128] = s_h @ W1[nt*128..]^T
        float4 c1lo[4], c1hi[4];
        #pragma unroll
        for (int rr = 0; rr < 4; ++rr) { c1lo[rr] = f4zero(); c1hi[rr] = f4zero(); }
        for (int kci = 0; kci < 8; ++kci) {   // KC=16
            #pragma unroll
            for (int i = 0; i < 2; ++i) {
                int idx = i * 256 + tid;
                int jj = idx >> 2, k4 = (idx & 3) * 4;
                float4 w = *reinterpret_cast<const float4*>(&W1[(size_t)(nt * 128 + jj) * 128 + kci * 16 + k4]);
                s_b[(k4 + 0) * 132 + jj] = w.x; s_b[(k4 + 1) * 132 + jj] = w.y;
                s_b[(k4 + 2) * 132 + jj] = w.z; s_b[(k4 + 3) * 132 + jj] = w.w;
            }
            __syncthreads();
            #pragma unroll
            for (int k4 = 0; k4 < 4; ++k4) {
                float4 a4[4];
                #pragma unroll
                for (int rr = 0; rr < 4; ++rr)
                    a4[rr] = *reinterpret_cast<const float4*>(&s_h[(r0 + rr) * 132 + kci * 16 + k4 * 4]);
                #pragma unroll
                for (int jj = 0; jj < 4; ++jj) {
                    float4 blo = *reinterpret_cast<const float4*>(&s_b[(k4 * 4 + jj) * 132 + cg * 4]);
                    float4 bhi = *reinterpret_cast<const float4*>(&s_b[(k4 * 4 + jj) * 132 + 64 + cg * 4]);
                    #pragma unroll
                    for (int rr = 0; rr < 4; ++rr) {
                        float av = (jj == 0) ? a4[rr].x : (jj == 1) ? a4[rr].y : (jj == 2) ? a4[rr].z : a4[rr].w;
                        f4fma(c1lo[rr], av, blo);
                        f4fma(c1hi[rr], av, bhi);
                    }
                }
            }
            __syncthreads();
        }
        // bias + gelu -> s_f
        {
            float4 blo = *reinterpret_cast<const float4*>(&b1[nt * 128 + cg * 4]);
            float4 bhi = *reinterpret_cast<const float4*>(&b1[nt * 128 + 64 + cg * 4]);
            #pragma unroll
            for (int rr = 0; rr < 4; ++rr) {
                float4 lo = c1lo[rr], hi = c1hi[rr];
                lo.x = gelu_exact(lo.x + blo.x); lo.y = gelu_exact(lo.y + blo.y);
                lo.z = gelu_exact(lo.z + blo.z); lo.w = gelu_exact(lo.w + blo.w);
                hi.x = gelu_exact(hi.x + bhi.x); hi.y = gelu_exact(hi.y + bhi.y);
                hi.z = gelu_exact(hi.z + bhi.z); hi.w = gelu_exact(hi.w + bhi.w);
                *reinterpret_cast<float4*>(&s_f[(r0 + rr) * 132 + cg * 4]) = lo;
                *reinterpret_cast<float4*>(&s_f[(r0 + rr) * 132 + 64 + cg * 4]) = hi;
            }
        }
        __syncthreads();
        // GEMM2: acc2 += s_f @ W2[:, nt*128..]^T
        for (int kci = 0; kci < 8; ++kci) {
            #pragma unroll
            for (int i = 0; i < 2; ++i) {
                int idx = i * 256 + tid;
                int jj = idx >> 2, k4 = (idx & 3) * 4;
                float4 w = *reinterpret_cast<const float4*>(&W2[(size_t)jj * FF_ + nt * 128 + kci * 16 + k4]);
                s_b[(k4 + 0) * 132 + jj] = w.x; s_b[(k4 + 1) * 132 + jj] = w.y;
                s_b[(k4 + 2) * 132 + jj] = w.z; s_b[(k4 + 3) * 132 + jj] = w.w;
            }
            __syncthreads();
            #pragma unroll
            for (int k4 = 0; k4 < 4; ++k4) {
                float4 a4[4];
                #pragma unroll
                for (int rr = 0; rr < 4; ++rr)
                    a4[rr] = *reinterpret_cast<const float4*>(&s_f[(r0 + rr) * 132 + kci * 16 + k4 * 4]);
                #pragma unroll
                for (int jj = 0; jj < 4; ++jj) {
                    float4 blo = *reinterpret_cast<const float4*>(&s_b[(k4 * 4 + jj) * 132 + cg * 4]);
                    float4 bhi = *reinterpret_cast<const float4*>(&s_b[(k4 * 4 + jj) * 132 + 64 + cg * 4]);
                    #pragma unroll
                    for (int rr = 0; rr < 4; ++rr) {
                        float av = (jj == 0) ? a4[rr].x : (jj == 1) ? a4[rr].y : (jj == 2) ? a4[rr].z : a4[rr].w;
                        f4fma(c2lo[rr], av, blo);
                        f4fma(c2hi[rr], av, bhi);
                    }
                }
            }
            __syncthreads();
        }
    }
    // epilogue: bias + residual(s_h) + LN2 -> hs
    float4 bblo = *reinterpret_cast<const float4*>(&b2[cg * 4]);
    float4 bbhi = *reinterpret_cast<const float4*>(&b2[64 + cg * 4]);
    float4 glo = *reinterpret_cast<const float4*>(&ln_g[(size_t)li * 128 + cg * 4]);
    float4 ghi = *reinterpret_cast<const float4*>(&ln_g[(size_t)li * 128 + 64 + cg * 4]);
    float4 lblo = *reinterpret_cast<const float4*>(&ln_b[(size_t)li * 128 + cg * 4]);
    float4 lbhi = *reinterpret_cast<const float4*>(&ln_b[(size_t)li * 128 + 64 + cg * 4]);
    #pragma unroll
    for (int rr = 0; rr < 4; ++rr) {
        size_t row = (size_t)node * 64 + r0 + rr;
        float4 rlo = *reinterpret_cast<const float4*>(&s_h[(r0 + rr) * 132 + cg * 4]);
        float4 rhi = *reinterpret_cast<const float4*>(&s_h[(r0 + rr) * 132 + 64 + cg * 4]);
        float4 lo = c2lo[rr], hi = c2hi[rr];
        lo.x += bblo.x + rlo.x; lo.y += bblo.y + rlo.y; lo.z += bblo.z + rlo.z; lo.w += bblo.w + rlo.w;
        hi.x += bbhi.x + rhi.x; hi.y += bbhi.y + rhi.y; hi.z += bbhi.z + rhi.z; hi.w += bbhi.w + rhi.w;
        float s = lo.x + lo.y + lo.z + lo.w + hi.x + hi.y + hi.z + hi.w;
        s += __shfl_xor(s, 1); s += __shfl_xor(s, 2); s += __shfl_xor(s, 4); s += __shfl_xor(s, 8);
        float mean = s * (1.0f / 128.0f);
        float4 dlo = make_float4(lo.x - mean, lo.y - mean, lo.z - mean, lo.w - mean);
        float4 dhi = make_float4(hi.x - mean, hi.y - mean, hi.z - mean, hi.w - mean);
        float vx = dlo.x * dlo.x + dlo.y * dlo.y + dlo.z * dlo.z + dlo.w * dlo.w +
                   dhi.x * dhi.x + dhi.y * dhi.y + dhi.z * dhi.z + dhi.w * dhi.w;
        vx += __shfl_xor(vx, 1); vx += __shfl_xor(vx, 2); vx += __shfl_xor(vx, 4); vx += __shfl_xor(vx, 8);
        float rstd = rsqrtf(vx * (1.0f / 128.0f) + 1e-5f);
        float4 olo = make_float4(dlo.x * rstd * glo.x + lblo.x, dlo.y * rstd * glo.y + lblo.y,
                                 dlo.z * rstd * glo.z + lblo.z, dlo.w * rstd * glo.w + lblo.w);
        float4 ohi = make_float4(dhi.x * rstd * ghi.x + lbhi.x, dhi.y * rstd * ghi.y + lbhi.y,
                                 dhi.z * rstd * ghi.z + lbhi.z, dhi.w * rstd * ghi.w + lbhi.w);
        *reinterpret_cast<float4*>(&hs[row * 128 + cg * 4]) = olo;
        *reinterpret_cast<float4*>(&hs[row * 128 + 64 + cg * 4]) = ohi;
    }
}

// ---------------- final LN -> out ----------------

__global__ __launch_bounds__(256) void k_fln(const float* __restrict__ hs, float* __restrict__ out,
                                             const float* __restrict__ g, const float* __restrict__ b) {
    int row = blockIdx.x * 4 + (threadIdx.x >> 6);
    int l = threadIdx.x & 63;
    float v0 = hs[(size_t)row * H_ + l];
    float v1 = hs[(size_t)row * H_ + 64 + l];
    float s = v0 + v1;
    #pragma unroll
    for (int off = 32; off; off >>= 1) s += __shfl_xor(s, off);
    float mean = s * (1.0f / H_);
    float d0 = v0 - mean, d1 = v1 - mean;
    float vs = d0 * d0 + d1 * d1;
    #pragma unroll
    for (int off = 32; off; off >>= 1) vs += __shfl_xor(vs, off);
    float rstd = rsqrtf(vs * (1.0f / H_) + 1e-5f);
    out[(size_t)row * H_ + l] = d0 * rstd * g[l] + b[l];
    out[(size_t)row * H_ + 64 + l] = d1 * rstd * g[64 + l] + b[64 + l];
}

// ---------------- launch ----------------

extern "C" void kernel_launch(void* const* d_in, const int* in_sizes, int n_in,
                              void* d_out, int out_size, void* d_ws, size_t ws_size,
                              hipStream_t stream) {
    const float* x          = (const float*)d_in[0];
    const int*   edge_index = (const int*)d_in[1];
    const int*   edge_type  = (const int*)d_in[2];
    const int*   node_type  = (const int*)d_in[3];
    const float* W_in    = (const float*)d_in[6];
    const float* b_in    = (const float*)d_in[7];
    const float* s_in_w  = (const float*)d_in[8];
    const float* s_in_b  = (const float*)d_in[9];
    const float* s_out_w = (const float*)d_in[10];
    const float* s_out_b = (const float*)d_in[11];
    const float* ln_s_g  = (const float*)d_in[12];
    const float* ln_s_b  = (const float*)d_in[13];
    const float* t_in_w  = (const float*)d_in[14];
    const float* t_in_b  = (const float*)d_in[15];
    const float* t_out_w = (const float*)d_in[16];
    const float* t_out_b = (const float*)d_in[17];
    const float* t_ln1_g = (const float*)d_in[18];
    const float* t_ln1_b = (const float*)d_in[19];
    const float* t_w1    = (const float*)d_in[20];
    const float* t_b1    = (const float*)d_in[21];
    const float* t_w2    = (const float*)d_in[22];
    const float* t_b2    = (const float*)d_in[23];
    const float* t_ln2_g = (const float*)d_in[24];
    const float* t_ln2_b = (const float*)d_in[25];
    const float* fin_g   = (const float*)d_in[26];
    const float* fin_b   = (const float*)d_in[27];
    float* out = (float*)d_out;

    // workspace layout (floats)
    float* h     = (float*)d_ws;                       // N*H = 8388608
    float* h_new = h + (size_t)N_ * H_;                // 8388608
    float* qkv   = h_new + (size_t)N_ * H_;            // E*384 = 11520000
    int* sorted  = (int*)(qkv + (size_t)E_ * 384);     // E
    int* gpos    = sorted + E_;                        // E
    int* gedge   = gpos + E_;                          // E
    int* cnt     = gedge + E_;                         // 64
    int* offs    = cnt + 64;                           // 64
    int* curs    = offs + 64;                          // 64
    int* nd64    = curs + 64;                          // 16
    int2* desc64 = (int2*)(nd64 + 16);                 // 544 int2

    // temporal chunk buffers (alias spatial regions, used after spatial completes)
    float* qc = qkv;                                   // CH*64*128 = 4194304
    float* kc = qkv + (size_t)CH_ * 64 * 128;          // 4194304
    float* vc = h_new;                                 // 4194304

    k_zero_cnt<<<1, 64, 0, stream>>>(cnt);
    k_hist<<<(E_ + 255) / 256, 256, 0, stream>>>(edge_index, edge_type, node_type, gedge, cnt);
    k_scan<<<1, 1, 0, stream>>>(cnt, offs, curs);
    k_scatter<<<(E_ + 255) / 256, 256, 0, stream>>>(gedge, curs, sorted, gpos);
    k_desc<<<1, 1, 0, stream>>>(offs, desc64, nd64);

    k_inproj<<<N_, 128, 0, stream>>>(x, node_type, W_in, b_in, h);

    for (int li = 0; li < L_; ++li) {
        k_zero<<<2048, 256, 0, stream>>>(h_new, N_ * H_);
        k_sqkv_gemm<<<dim3(544, 3), 256, 0, stream>>>(h, s_in_w, s_in_b, sorted, offs, edge_index,
                                                      desc64, nd64, qkv, li);
        k_gattn<<<544, 256, 0, stream>>>(qkv, sorted, offs, edge_index, desc64, nd64,
                                         s_out_w, s_out_b, h_new, li);
        k_lngelu<<<N_, 64, 0, stream>>>(h_new, h, ln_s_g, ln_s_b, li);
    }

    // temporal: hs = h + PE (in place)
    k_peadd<<<2048, 256, 0, stream>>>(h);
    for (int li = 0; li < TL_; ++li) {
        for (int c = 0; c < NB_ / CH_; ++c) {
            int c0 = c * CH_;
            k_tqkv<<<dim3(CH_, 3), 256, 0, stream>>>(h, t_in_w, t_in_b, qc, kc, vc, li, c0);
            k_tattn<<<dim3(CH_, NH_), 64, 0, stream>>>(qc, kc, vc);
            k_toutln<<<CH_, 256, 0, stream>>>(qc, h, t_out_w, t_out_b, t_ln1_g, t_ln1_b, li, c0);
        }
        k_tff<<<NB_, 256, 0, stream>>>(h, t_w1, t_b1, t_w2, t_b2, t_ln2_g, t_ln2_b, li);
    }
    k_fln<<<N_ / 4, 256, 0, stream>>>(h, out, fin_g, fin_b);
}